// Round 4
// baseline (708.388 us; speedup 1.0000x reference)
//
#include <hip/hip_runtime.h>
#include <hip/hip_bf16.h>

typedef __attribute__((ext_vector_type(8))) short short8;
typedef __attribute__((ext_vector_type(4))) float f32x4;

constexpr int cB = 4, cN = 8192, cC = 512, cH = 8, cD = 64;
constexpr int cM = cB * cN;        // 32768 tokens
constexpr int cHD = cH * cD;       // 512
constexpr int cBH = cB * cH;       // 32
constexpr float kEPS = 1e-6f;

// ---- split f32 -> (bf16 hi by truncation, bf16 lo of remainder) ----
__device__ __forceinline__ void split2(float f, ushort& h, ushort& l) {
  unsigned u = __float_as_uint(f);
  h = (ushort)(u >> 16);
  float fl = f - __uint_as_float(u & 0xffff0000u);
  l = (ushort)(__float_as_uint(fl) >> 16);
}
__device__ __forceinline__ int pack_hi(float a, float b) {
  return (int)((__float_as_uint(a) >> 16) | (__float_as_uint(b) & 0xffff0000u));
}
__device__ __forceinline__ int pack_lo(float a, float b) {
  float la = a - __uint_as_float(__float_as_uint(a) & 0xffff0000u);
  float lb = b - __uint_as_float(__float_as_uint(b) & 0xffff0000u);
  return (int)((__float_as_uint(la) >> 16) | (__float_as_uint(lb) & 0xffff0000u));
}

// ---------------- splitter: f32 -> bf16 hi/lo ----------------
__global__ __launch_bounds__(256) void split_w(const float* __restrict__ src,
    ushort* __restrict__ hi, ushort* __restrict__ lo, int n4) {
  int i = blockIdx.x * 256 + threadIdx.x;
  if (i >= n4) return;
  float4 v = reinterpret_cast<const float4*>(src)[i];
  ushort4 h, l;
  split2(v.x, h.x, l.x); split2(v.y, h.y, l.y);
  split2(v.z, h.z, l.z); split2(v.w, h.w, l.w);
  reinterpret_cast<ushort4*>(hi)[i] = h;
  reinterpret_cast<ushort4*>(lo)[i] = l;
}

// ---------------- split-bf16 MFMA GEMM: C = A[Mx512] @ W[NCx512]^T ----------------
// PRE=true : A pre-split bf16 hi/lo via global_load_lds with XOR-swizzled source
//            (LDS linear; read applies same XOR -> 2-way banks, rule #21).
// PRE=false: A f32 reg-staged + converted (padded LDS) — fallback if ws too small.
// B always PRE-split, swizzled-staged.
// EPI=0: scatter qkv (sigmoid q,k; v*0.125) -> [B,H,N,D] slabs + fused qsum/ksum.
// EPI=1: out = acc + bias.
template<int EPI, bool PRE>
__global__ __launch_bounds__(256) void gemm_mfma(
    const float* __restrict__ A,
    const ushort* __restrict__ Ah_g, const ushort* __restrict__ Al_g,
    const ushort* __restrict__ Wh, const ushort* __restrict__ Wl,
    const float* __restrict__ bias,
    float* __restrict__ o0, float* __restrict__ o1, float* __restrict__ o2,
    float* __restrict__ qsum, float* __restrict__ ksum) {
  constexpr int BM = 128, BN = 128, BK = 32;
  constexpr int LDA = PRE ? 32 : 40;           // pad only the converted path
  __shared__ ushort Ah[BM * LDA], Al[BM * LDA];
  __shared__ ushort Bh[BN * 32], Bl[BN * 32];  // linear (global_load_lds dest)
  __shared__ float colsum[128];
  const int t = threadIdx.x;
  const int wave = t >> 6, lane = t & 63;
  const int wm = wave >> 1, wn = wave & 1;     // 2x2 waves of 64x64
  const int row0 = blockIdx.x * BM, col0 = blockIdx.y * BN;
  const int l15 = lane & 15, lg = lane >> 4;

  if (EPI == 0 && t < 128) colsum[t] = 0.f;    // ordered by first loop barrier

  f32x4 acc[4][4] = {};

  const int arow = t >> 1, akh = (t & 1) * 16;           // A-stage mapping (f32 path)
  const float* aptr = PRE ? nullptr : (A + (size_t)(row0 + arow) * cC + akh);
  const int srow = lane >> 2, sunit = lane & 3;          // glds stage lane mapping

  for (int k0 = 0; k0 < cC; k0 += BK) {
    __syncthreads();
    if (!PRE) {
      // ---- stage A: 16 f32 -> bf16 hi/lo, padded LDS ----
      const float4 fa = *(const float4*)(aptr + k0 + 0);
      const float4 fb = *(const float4*)(aptr + k0 + 4);
      const float4 fc = *(const float4*)(aptr + k0 + 8);
      const float4 fd = *(const float4*)(aptr + k0 + 12);
      int4 H0 = make_int4(pack_hi(fa.x, fa.y), pack_hi(fa.z, fa.w),
                          pack_hi(fb.x, fb.y), pack_hi(fb.z, fb.w));
      int4 H1 = make_int4(pack_hi(fc.x, fc.y), pack_hi(fc.z, fc.w),
                          pack_hi(fd.x, fd.y), pack_hi(fd.z, fd.w));
      int4 L0 = make_int4(pack_lo(fa.x, fa.y), pack_lo(fa.z, fa.w),
                          pack_lo(fb.x, fb.y), pack_lo(fb.z, fb.w));
      int4 L1 = make_int4(pack_lo(fc.x, fc.y), pack_lo(fc.z, fc.w),
                          pack_lo(fd.x, fd.y), pack_lo(fd.z, fd.w));
      *reinterpret_cast<int4*>(&Ah[arow * LDA + akh]) = H0;
      *reinterpret_cast<int4*>(&Ah[arow * LDA + akh + 8]) = H1;
      *reinterpret_cast<int4*>(&Al[arow * LDA + akh]) = L0;
      *reinterpret_cast<int4*>(&Al[arow * LDA + akh + 8]) = L1;
    } else {
      // ---- stage A: global_load_lds, source-unit XOR-swizzled ----
      #pragma unroll
      for (int hh = 0; hh < 2; ++hh) {
        const int ar = wave * 32 + hh * 16 + srow;
        const int sw = sunit ^ ((ar >> 1) & 3);
        const size_t goff = (size_t)(row0 + ar) * cC + k0 + sw * 8;
        __builtin_amdgcn_global_load_lds(
            (const __attribute__((address_space(1))) void*)(Ah_g + goff),
            (__attribute__((address_space(3))) void*)(&Ah[(wave * 32 + hh * 16) * 32]),
            16, 0, 0);
        __builtin_amdgcn_global_load_lds(
            (const __attribute__((address_space(1))) void*)(Al_g + goff),
            (__attribute__((address_space(3))) void*)(&Al[(wave * 32 + hh * 16) * 32]),
            16, 0, 0);
      }
    }
    // ---- stage B: global_load_lds, source-unit XOR-swizzled ----
    #pragma unroll
    for (int hh = 0; hh < 2; ++hh) {
      const int br = wave * 32 + hh * 16 + srow;
      const int sw = sunit ^ ((br >> 1) & 3);
      const size_t goff = (size_t)(col0 + br) * cC + k0 + sw * 8;
      __builtin_amdgcn_global_load_lds(
          (const __attribute__((address_space(1))) void*)(Wh + goff),
          (__attribute__((address_space(3))) void*)(&Bh[(wave * 32 + hh * 16) * 32]),
          16, 0, 0);
      __builtin_amdgcn_global_load_lds(
          (const __attribute__((address_space(1))) void*)(Wl + goff),
          (__attribute__((address_space(3))) void*)(&Bl[(wave * 32 + hh * 16) * 32]),
          16, 0, 0);
    }
    __syncthreads();
    // ---- fragments + 3-product MFMA ----
    short8 ah[4], al[4];
    #pragma unroll
    for (int mi = 0; mi < 4; ++mi) {
      const int r = wm * 64 + mi * 16 + l15;
      const int aidx = PRE ? (r * 32 + (lg ^ ((r >> 1) & 3)) * 8) : (r * LDA + lg * 8);
      ah[mi] = *reinterpret_cast<const short8*>(&Ah[aidx]);
      al[mi] = *reinterpret_cast<const short8*>(&Al[aidx]);
    }
    #pragma unroll
    for (int ni = 0; ni < 4; ++ni) {
      const int c = wn * 64 + ni * 16 + l15;
      const int bidx = c * 32 + (lg ^ ((c >> 1) & 3)) * 8;
      const short8 bh = *reinterpret_cast<const short8*>(&Bh[bidx]);
      const short8 bl = *reinterpret_cast<const short8*>(&Bl[bidx]);
      #pragma unroll
      for (int mi = 0; mi < 4; ++mi) {
        acc[mi][ni] = __builtin_amdgcn_mfma_f32_16x16x32_bf16(ah[mi], bh, acc[mi][ni], 0, 0, 0);
        acc[mi][ni] = __builtin_amdgcn_mfma_f32_16x16x32_bf16(al[mi], bh, acc[mi][ni], 0, 0, 0);
        acc[mi][ni] = __builtin_amdgcn_mfma_f32_16x16x32_bf16(ah[mi], bl, acc[mi][ni], 0, 0, 0);
      }
    }
  }
  // ---- epilogue: C/D map col=lane&15, row=(lane>>4)*4+r ----
  const bool qk_block = (EPI == 0) && (blockIdx.y < 8);
  float csum[4] = {};
  #pragma unroll
  for (int mi = 0; mi < 4; ++mi) {
    #pragma unroll
    for (int ni = 0; ni < 4; ++ni) {
      const int col = col0 + wn * 64 + ni * 16 + l15;
      #pragma unroll
      for (int r = 0; r < 4; ++r) {
        const int m = row0 + wm * 64 + mi * 16 + lg * 4 + r;
        const float val = acc[mi][ni][r];
        if (EPI == 0) {
          const int which = col >> 9;
          const int c2 = col & 511;
          const int h = c2 >> 6, d = c2 & 63;
          const int bb = m >> 13, n = m & 8191;
          const size_t idx = (((size_t)(bb * cH + h)) * cN + n) * cD + d;
          if (which < 2) {
            const float sv = 1.f / (1.f + __expf(-val));
            if (which == 0) o0[idx] = sv; else o1[idx] = sv;
            csum[ni] += sv;
          } else {
            o2[idx] = val * 0.125f;
          }
        } else {
          o0[(size_t)m * cC + col] = val + bias[col];
        }
      }
    }
  }
  if (qk_block) {
    #pragma unroll
    for (int ni = 0; ni < 4; ++ni)
      atomicAdd(&colsum[wn * 64 + ni * 16 + l15], csum[ni]);
    __syncthreads();
    if (t < 128) {
      const int col = col0 + t;
      const int c2 = col & 511;
      const int h = c2 >> 6, d = c2 & 63;
      const int bb = row0 >> 13;
      float* tgt = (col < 512) ? qsum : ksum;
      atomicAdd(&tgt[(bb * cH + h) * cD + d], colsum[t]);
    }
  }
}

// ---------------- K34: si, so; accumulate Sq, Sk (4 rows/wave/iter, float4) ----------------
__global__ __launch_bounds__(256) void k34_flow(const float* __restrict__ q,
      const float* __restrict__ k, const float* __restrict__ qsum,
      const float* __restrict__ ksum, float* __restrict__ si,
      float* __restrict__ Sq, float* __restrict__ Sk) {
  const int bh = blockIdx.x;
  const int n0 = blockIdx.y * 256;
  const int t = threadIdx.x;
  const int wave = t >> 6, lane = t & 63;
  const int g = lane >> 4, j = lane & 15;
  const float* qb = q + (size_t)bh * cN * cD;
  const float* kb = k + (size_t)bh * cN * cD;
  const float4 ks4 = *(const float4*)&ksum[bh * 64 + j * 4];
  const float4 qs4 = *(const float4*)&qsum[bh * 64 + j * 4];
  const float ksd[4] = {ks4.x + kEPS, ks4.y + kEPS, ks4.z + kEPS, ks4.w + kEPS};
  const float qsd[4] = {qs4.x + kEPS, qs4.y + kEPS, qs4.z + kEPS, qs4.w + kEPS};
  float aSq[4] = {}, aSk[4] = {};
  for (int i = 0; i < 16; ++i) {
    const int n = n0 + wave * 64 + i * 4 + g;
    const float4 q4 = *(const float4*)&qb[(size_t)n * cD + j * 4];
    const float4 k4 = *(const float4*)&kb[(size_t)n * cD + j * 4];
    const float qa[4] = {q4.x, q4.y, q4.z, q4.w};
    const float ka[4] = {k4.x, k4.y, k4.z, k4.w};
    float t1 = 0.f, t2 = 0.f;
    #pragma unroll
    for (int c = 0; c < 4; ++c) {
      t1 = fmaf(qa[c] + kEPS, ksd[c], t1);
      t2 = fmaf(ka[c] + kEPS, qsd[c], t2);
    }
    #pragma unroll
    for (int off = 1; off < 16; off <<= 1) {
      t1 += __shfl_xor(t1, off);
      t2 += __shfl_xor(t2, off);
    }
    const float si_n = 1.f / (t1 + kEPS);
    const float so_n = 1.f / (t2 + kEPS);
    if (j == 0) si[(size_t)bh * cN + n] = si_n;
    #pragma unroll
    for (int c = 0; c < 4; ++c) {
      aSq[c] = fmaf(qa[c], si_n, aSq[c]);
      aSk[c] = fmaf(ka[c], so_n, aSk[c]);
    }
  }
  #pragma unroll
  for (int c = 0; c < 4; ++c) {
    aSq[c] += __shfl_xor(aSq[c], 16); aSq[c] += __shfl_xor(aSq[c], 32);
    aSk[c] += __shfl_xor(aSk[c], 16); aSk[c] += __shfl_xor(aSk[c], 32);
  }
  __shared__ float sAq[4][64], sAk[4][64];
  if (g == 0) {
    #pragma unroll
    for (int c = 0; c < 4; ++c) { sAq[wave][j * 4 + c] = aSq[c]; sAk[wave][j * 4 + c] = aSk[c]; }
  }
  __syncthreads();
  if (t < 64) {
    atomicAdd(&Sq[bh * 64 + t], sAq[0][t] + sAq[1][t] + sAq[2][t] + sAq[3][t]);
    atomicAdd(&Sk[bh * 64 + t], sAk[0][t] + sAk[1][t] + sAk[2][t] + sAk[3][t]);
  }
}

// ---------------- K45: ev inline (parallel); kv' = sum_n (k*ev) (x) v ; Z ----------------
__global__ __launch_bounds__(256) void k45_kv(const float* __restrict__ kk_,
      const float* __restrict__ vv, const float* __restrict__ Sq,
      float* __restrict__ kvout, float* __restrict__ Zb) {
  const int bh = blockIdx.x;
  constexpr int ROWS = 256;                  // grid.y = 32
  const int n0 = blockIdx.y * ROWS;
  const int t = threadIdx.x;
  const int d = t & 63, eb = t >> 6;
  const int g = t >> 4, j = t & 15;          // 16 ev-groups of 16 lanes
  const float* kb = kk_ + (size_t)bh * cN * cD;
  const float* vb = vv + (size_t)bh * cN * cD;
  const float4 sq4 = *(const float4*)&Sq[bh * 64 + j * 4];
  const float SqE[4] = {sq4.x + kEPS, sq4.y + kEPS, sq4.z + kEPS, sq4.w + kEPS};
  __shared__ float ks[16][64];
  __shared__ float vs[16][64];
  __shared__ float evs[16];
  __shared__ float zl[16];
  float acc[16] = {};
  float zsum = 0.f;
  for (int c0 = 0; c0 < ROWS; c0 += 16) {
    __syncthreads();
    {
      const int r = t >> 4, c4 = (t & 15) * 4;
      *(float4*)&ks[r][c4] = *(const float4*)&kb[(size_t)(n0 + c0 + r) * cD + c4];
      *(float4*)&vs[r][c4] = *(const float4*)&vb[(size_t)(n0 + c0 + r) * cD + c4];
    }
    __syncthreads();
    {
      const float4 kk4 = *(const float4*)&ks[g][j * 4];
      float tt = 0.f;
      tt = fmaf(kk4.x + kEPS, SqE[0], tt);
      tt = fmaf(kk4.y + kEPS, SqE[1], tt);
      tt = fmaf(kk4.z + kEPS, SqE[2], tt);
      tt = fmaf(kk4.w + kEPS, SqE[3], tt);
      #pragma unroll
      for (int off = 1; off < 16; off <<= 1) tt += __shfl_xor(tt, off);
      if (j == 0) {
        const float cs = fminf(fmaxf(tt + kEPS, -1.f), 1.f);
        const float e = __expf(cs);
        evs[g] = e;
        zsum += e;
      }
    }
    __syncthreads();
    #pragma unroll
    for (int r = 0; r < 16; ++r) {
      const float kd = ks[r][d] * evs[r];
      #pragma unroll
      for (int j2 = 0; j2 < 16; ++j2)
        acc[j2] = fmaf(kd, vs[r][eb * 16 + j2], acc[j2]);
    }
  }
  if (j == 0) zl[g] = zsum;
  __syncthreads();
  if (t == 0) {
    float z = 0.f;
    #pragma unroll
    for (int i = 0; i < 16; ++i) z += zl[i];
    atomicAdd(&Zb[bh], z);
  }
  float* kvb = kvout + (size_t)bh * cD * cD + (size_t)d * cD + eb * 16;
  #pragma unroll
  for (int j2 = 0; j2 < 16; ++j2) atomicAdd(&kvb[j2], acc[j2]);
}

// ---------------- K6b: xu = (q @ kv*(N/Z)) * si * sa -> split bf16 [M][512] ----------------
__global__ __launch_bounds__(256) void k6b_xu(const float* __restrict__ q,
      const float* __restrict__ kvmat, const float* __restrict__ si,
      const float* __restrict__ Sk, const float* __restrict__ Zb,
      ushort* __restrict__ xh, ushort* __restrict__ xl) {
  const int bh = blockIdx.x;
  const int b = bh >> 3, head = bh & 7;
  const int n0 = blockIdx.y * 64;
  const int lane = threadIdx.x & 63;
  const int wave = threadIdx.x >> 6;
  __shared__ float kvs[64][64];
  const float zs = (float)cN / Zb[bh];
  for (int i = threadIdx.x; i < 4096; i += 256)
    kvs[i >> 6][i & 63] = kvmat[(size_t)bh * 4096 + i] * zs;
  const float SkE = Sk[bh * 64 + lane] + kEPS;
  __syncthreads();
  const float* qb = q + (size_t)bh * cN * cD;
  for (int i = 0; i < 16; ++i) {
    const int n = n0 + wave * 16 + i;
    const float qd = qb[(size_t)n * cD + lane];
    float t2 = (qd + kEPS) * SkE;
    #pragma unroll
    for (int off = 1; off < 64; off <<= 1) t2 += __shfl_xor(t2, off);
    const float sa_n = 1.f / (1.f + __expf(-(t2 + kEPS)));
    float a0 = 0.f, a1 = 0.f, a2 = 0.f, a3 = 0.f;
    #pragma unroll
    for (int dd = 0; dd < 64; dd += 4) {
      a0 = fmaf(__shfl(qd, dd),     kvs[dd][lane],     a0);
      a1 = fmaf(__shfl(qd, dd + 1), kvs[dd + 1][lane], a1);
      a2 = fmaf(__shfl(qd, dd + 2), kvs[dd + 2][lane], a2);
      a3 = fmaf(__shfl(qd, dd + 3), kvs[dd + 3][lane], a3);
    }
    const float s = si[(size_t)bh * cN + n] * sa_n;
    const float val = ((a0 + a1) + (a2 + a3)) * s;
    ushort hbits, lbits;
    split2(val, hbits, lbits);
    const size_t m = (size_t)b * cN + n;
    xh[m * cC + head * 64 + lane] = hbits;
    xl[m * cC + head * 64 + lane] = lbits;
  }
}

extern "C" void kernel_launch(void* const* d_in, const int* in_sizes, int n_in,
                              void* d_out, int out_size, void* d_ws, size_t ws_size,
                              hipStream_t stream) {
  (void)in_sizes; (void)n_in; (void)out_size;
  const float* x     = (const float*)d_in[0];
  const float* Wqkv  = (const float*)d_in[1];
  const float* Wproj = (const float*)d_in[2];
  const float* bproj = (const float*)d_in[3];
  float* out = (float*)d_out;
  float* ws  = (float*)d_ws;

  const size_t SLAB = (size_t)cBH * cN * cD;       // 16,777,216 floats
  const size_t OFF_Q   = 0;
  const size_t OFF_K   = SLAB;
  const size_t OFF_V   = 2 * SLAB;                 // xu hi/lo alias v (dead after K45)
  const size_t OFF_ACC = 3 * SLAB;
  const size_t ACC_FLOATS = 2048 * 4 + 32 + (size_t)cBH * cD * cD;
  const size_t OFF_SI  = OFF_ACC + ACC_FLOATS;
  const size_t OFF_SA  = OFF_SI + (size_t)cBH * cN;
  const size_t OFF_EV  = OFF_SA + (size_t)cBH * cN;
  const size_t TOTAL   = OFF_EV + (size_t)cBH * cN;          // ~196 MiB
  const size_t OFF_XS  = TOTAL;
  const size_t TOTAL_PRE = OFF_XS + (size_t)cM * cC;         // + 64 MiB (xs hi+lo)
  if (ws_size < TOTAL * sizeof(float)) return;
  const bool usePre = ws_size >= TOTAL_PRE * sizeof(float);

  float* q    = ws + OFF_Q;
  float* k    = ws + OFF_K;
  float* v    = ws + OFF_V;
  float* ksum = ws + OFF_ACC;
  float* qsum = ksum + 2048;
  float* Sk   = ksum + 4096;
  float* Sq   = ksum + 6144;
  float* Zb   = ksum + 8192;
  float* kvm  = ksum + 8224;
  float* si   = ws + OFF_SI;

  // xu bf16 hi/lo overlay the v slab (v dead after K45)
  ushort* xh = (ushort*)(ws + OFF_V);
  ushort* xl = xh + (size_t)cM * cHD;

  // W splits alias the si region (wq dead after gemm0, before K34 writes si;
  // wp written after k6b has consumed si)
  ushort* wqh = (ushort*)(ws + OFF_SI);
  ushort* wql = wqh + (size_t)3 * cHD * cC;
  ushort* wph = (ushort*)(ws + OFF_SI);
  ushort* wpl = wph + (size_t)cC * cHD;

  // x pre-split slabs (only if ws allows)
  ushort* xsh = (ushort*)(ws + OFF_XS);
  ushort* xsl = xsh + (size_t)cM * cC;

  hipMemsetAsync(ksum, 0, ACC_FLOATS * sizeof(float), stream);

  split_w<<<(3 * cHD * cC / 4 + 255) / 256, 256, 0, stream>>>(Wqkv, wqh, wql, 3 * cHD * cC / 4);
  if (usePre) {
    split_w<<<((size_t)cM * cC / 4 + 255) / 256, 256, 0, stream>>>(x, xsh, xsl, cM * cC / 4);
    gemm_mfma<0, true><<<dim3(cM / 128, (3 * cHD) / 128), 256, 0, stream>>>(
        nullptr, xsh, xsl, wqh, wql, nullptr, q, k, v, qsum, ksum);
  } else {
    gemm_mfma<0, false><<<dim3(cM / 128, (3 * cHD) / 128), 256, 0, stream>>>(
        x, nullptr, nullptr, wqh, wql, nullptr, q, k, v, qsum, ksum);
  }
  k34_flow<<<dim3(cBH, cN / 256), 256, 0, stream>>>(q, k, qsum, ksum, si, Sq, Sk);
  k45_kv<<<dim3(cBH, cN / 256), 256, 0, stream>>>(k, v, Sq, kvm, Zb);
  k6b_xu<<<dim3(cBH, cN / 64), 256, 0, stream>>>(q, kvm, si, Sk, Zb, xh, xl);
  split_w<<<(cC * cHD / 4 + 255) / 256, 256, 0, stream>>>(Wproj, wph, wpl, cC * cHD / 4);
  gemm_mfma<1, true><<<dim3(cM / 128, cHD / 128), 256, 0, stream>>>(
      nullptr, xh, xl, wph, wpl, bproj, out, nullptr, nullptr, nullptr, nullptr);
}

// Round 5
// 550.229 us; speedup vs baseline: 1.2874x; 1.2874x over previous
//
#include <hip/hip_runtime.h>
#include <hip/hip_bf16.h>

typedef __attribute__((ext_vector_type(8))) short short8;
typedef __attribute__((ext_vector_type(4))) float f32x4;

constexpr int cB = 4, cN = 8192, cC = 512, cH = 8, cD = 64;
constexpr int cM = cB * cN;        // 32768 tokens
constexpr int cHD = cH * cD;       // 512
constexpr int cBH = cB * cH;       // 32
constexpr float kEPS = 1e-6f;
constexpr int KV_SPLIT = 32;       // k45 split-K slices

// ---- split f32 -> (bf16 hi by truncation, bf16 lo of remainder) ----
__device__ __forceinline__ void split2(float f, ushort& h, ushort& l) {
  unsigned u = __float_as_uint(f);
  h = (ushort)(u >> 16);
  float fl = f - __uint_as_float(u & 0xffff0000u);
  l = (ushort)(__float_as_uint(fl) >> 16);
}
__device__ __forceinline__ int pack_hi(float a, float b) {
  return (int)((__float_as_uint(a) >> 16) | (__float_as_uint(b) & 0xffff0000u));
}
__device__ __forceinline__ int pack_lo(float a, float b) {
  float la = a - __uint_as_float(__float_as_uint(a) & 0xffff0000u);
  float lb = b - __uint_as_float(__float_as_uint(b) & 0xffff0000u);
  return (int)((__float_as_uint(la) >> 16) | (__float_as_uint(lb) & 0xffff0000u));
}

// ---------------- splitter: f32 -> bf16 hi/lo (weights only) ----------------
__global__ __launch_bounds__(256) void split_w(const float* __restrict__ src,
    ushort* __restrict__ hi, ushort* __restrict__ lo, int n4) {
  int i = blockIdx.x * 256 + threadIdx.x;
  if (i >= n4) return;
  float4 v = reinterpret_cast<const float4*>(src)[i];
  ushort4 h, l;
  split2(v.x, h.x, l.x); split2(v.y, h.y, l.y);
  split2(v.z, h.z, l.z); split2(v.w, h.w, l.w);
  reinterpret_cast<ushort4*>(hi)[i] = h;
  reinterpret_cast<ushort4*>(lo)[i] = l;
}

// ---------------- split-bf16 MFMA GEMM: C = A[Mx512] @ W[NCx512]^T ----------------
// EPI=0: A is f32, staged raw via global_load_lds (unit-XOR swizzled source),
//        converted to bf16 hi/lo at fragment load. Epilogue scatters qkv
//        (sigmoid q,k; v*0.125) to [B,H,N,D] + fused qsum/ksum.
// EPI=1: A is pre-split bf16 hi/lo (from k6b), global_load_lds staged.
//        Epilogue: out = acc + bias.
template<int EPI>
__global__ __launch_bounds__(256) void gemm_mfma(
    const float* __restrict__ A,
    const ushort* __restrict__ Ah_g, const ushort* __restrict__ Al_g,
    const ushort* __restrict__ Wh, const ushort* __restrict__ Wl,
    const float* __restrict__ bias,
    float* __restrict__ o0, float* __restrict__ o1, float* __restrict__ o2,
    float* __restrict__ qsum, float* __restrict__ ksum) {
  constexpr bool AF32 = (EPI == 0);
  constexpr int BM = 128, BN = 128, BK = 32;
  __shared__ float smemf[8192];                 // 32 KB, time-shared layout
  float*  Asf = smemf;                          // AF32: f32 A tile (16 KB)
  ushort* Ah  = (ushort*)smemf;                 // !AF32: bf16 hi (8 KB)
  ushort* Al  = (ushort*)(smemf + 2048);        // !AF32: bf16 lo (8 KB)
  ushort* Bh  = (ushort*)(smemf + 4096);        // 8 KB
  ushort* Bl  = (ushort*)(smemf + 6144);        // 8 KB
  __shared__ float colsum[128];
  const int t = threadIdx.x;
  const int wave = t >> 6, lane = t & 63;
  const int wm = wave >> 1, wn = wave & 1;      // 2x2 waves of 64x64
  const int row0 = blockIdx.x * BM, col0 = blockIdx.y * BN;
  const int l15 = lane & 15, lg = lane >> 4;

  if (EPI == 0 && t < 128) colsum[t] = 0.f;     // ordered by first loop barrier

  f32x4 acc[4][4] = {};

  const int srow = lane >> 2, sunit = lane & 3; // bf16 stage mapping (4x16B/row)
  const int arowf = lane >> 3;                  // f32 stage: row-in-8 block
  const int acolf = ((lane & 7) ^ (lane >> 3)) * 4;  // swizzled f32 source col

  for (int k0 = 0; k0 < cC; k0 += BK) {
    __syncthreads();
    if (AF32) {
      // ---- stage A: raw f32, 4 calls x 1KB/wave, source-unit XOR swizzle ----
      #pragma unroll
      for (int c2 = 0; c2 < 4; ++c2) {
        const int row = wave * 32 + c2 * 8 + arowf;
        __builtin_amdgcn_global_load_lds(
            (const __attribute__((address_space(1))) void*)(A + (size_t)(row0 + row) * cC + k0 + acolf),
            (__attribute__((address_space(3))) void*)(&Asf[(wave * 4 + c2) * 256]),
            16, 0, 0);
      }
    } else {
      // ---- stage A: pre-split bf16 hi/lo, source-unit XOR swizzle ----
      #pragma unroll
      for (int hh = 0; hh < 2; ++hh) {
        const int ar = wave * 32 + hh * 16 + srow;
        const int sw = sunit ^ ((ar >> 1) & 3);
        const size_t goff = (size_t)(row0 + ar) * cC + k0 + sw * 8;
        __builtin_amdgcn_global_load_lds(
            (const __attribute__((address_space(1))) void*)(Ah_g + goff),
            (__attribute__((address_space(3))) void*)(&Ah[(wave * 32 + hh * 16) * 32]),
            16, 0, 0);
        __builtin_amdgcn_global_load_lds(
            (const __attribute__((address_space(1))) void*)(Al_g + goff),
            (__attribute__((address_space(3))) void*)(&Al[(wave * 32 + hh * 16) * 32]),
            16, 0, 0);
      }
    }
    // ---- stage B: pre-split bf16 hi/lo, source-unit XOR swizzle ----
    #pragma unroll
    for (int hh = 0; hh < 2; ++hh) {
      const int br = wave * 32 + hh * 16 + srow;
      const int sw = sunit ^ ((br >> 1) & 3);
      const size_t goff = (size_t)(col0 + br) * cC + k0 + sw * 8;
      __builtin_amdgcn_global_load_lds(
          (const __attribute__((address_space(1))) void*)(Wh + goff),
          (__attribute__((address_space(3))) void*)(&Bh[(wave * 32 + hh * 16) * 32]),
          16, 0, 0);
      __builtin_amdgcn_global_load_lds(
          (const __attribute__((address_space(1))) void*)(Wl + goff),
          (__attribute__((address_space(3))) void*)(&Bl[(wave * 32 + hh * 16) * 32]),
          16, 0, 0);
    }
    __syncthreads();
    // ---- fragments + 3-product MFMA ----
    short8 ah[4], al[4];
    #pragma unroll
    for (int mi = 0; mi < 4; ++mi) {
      const int r = wm * 64 + mi * 16 + l15;
      if (AF32) {
        const int key = r & 7;
        const float4 fa = *reinterpret_cast<const float4*>(&Asf[r * 32 + (((lg * 2) ^ key) << 2)]);
        const float4 fb = *reinterpret_cast<const float4*>(&Asf[r * 32 + (((lg * 2 + 1) ^ key) << 2)]);
        int4 H = make_int4(pack_hi(fa.x, fa.y), pack_hi(fa.z, fa.w),
                           pack_hi(fb.x, fb.y), pack_hi(fb.z, fb.w));
        int4 L = make_int4(pack_lo(fa.x, fa.y), pack_lo(fa.z, fa.w),
                           pack_lo(fb.x, fb.y), pack_lo(fb.z, fb.w));
        ah[mi] = *reinterpret_cast<short8*>(&H);
        al[mi] = *reinterpret_cast<short8*>(&L);
      } else {
        const int aidx = r * 32 + (lg ^ ((r >> 1) & 3)) * 8;
        ah[mi] = *reinterpret_cast<const short8*>(&Ah[aidx]);
        al[mi] = *reinterpret_cast<const short8*>(&Al[aidx]);
      }
    }
    #pragma unroll
    for (int ni = 0; ni < 4; ++ni) {
      const int c = wn * 64 + ni * 16 + l15;
      const int bidx = c * 32 + (lg ^ ((c >> 1) & 3)) * 8;
      const short8 bh = *reinterpret_cast<const short8*>(&Bh[bidx]);
      const short8 bl = *reinterpret_cast<const short8*>(&Bl[bidx]);
      #pragma unroll
      for (int mi = 0; mi < 4; ++mi) {
        acc[mi][ni] = __builtin_amdgcn_mfma_f32_16x16x32_bf16(ah[mi], bh, acc[mi][ni], 0, 0, 0);
        acc[mi][ni] = __builtin_amdgcn_mfma_f32_16x16x32_bf16(al[mi], bh, acc[mi][ni], 0, 0, 0);
        acc[mi][ni] = __builtin_amdgcn_mfma_f32_16x16x32_bf16(ah[mi], bl, acc[mi][ni], 0, 0, 0);
      }
    }
  }
  // ---- epilogue: C/D map col=lane&15, row=(lane>>4)*4+r ----
  const bool qk_block = (EPI == 0) && (blockIdx.y < 8);
  float csum[4] = {};
  #pragma unroll
  for (int mi = 0; mi < 4; ++mi) {
    #pragma unroll
    for (int ni = 0; ni < 4; ++ni) {
      const int col = col0 + wn * 64 + ni * 16 + l15;
      #pragma unroll
      for (int r = 0; r < 4; ++r) {
        const int m = row0 + wm * 64 + mi * 16 + lg * 4 + r;
        const float val = acc[mi][ni][r];
        if (EPI == 0) {
          const int which = col >> 9;
          const int c2 = col & 511;
          const int h = c2 >> 6, d = c2 & 63;
          const int bb = m >> 13, n = m & 8191;
          const size_t idx = (((size_t)(bb * cH + h)) * cN + n) * cD + d;
          if (which < 2) {
            const float sv = 1.f / (1.f + __expf(-val));
            if (which == 0) o0[idx] = sv; else o1[idx] = sv;
            csum[ni] += sv;
          } else {
            o2[idx] = val * 0.125f;
          }
        } else {
          o0[(size_t)m * cC + col] = val + bias[col];
        }
      }
    }
  }
  if (qk_block) {
    #pragma unroll
    for (int ni = 0; ni < 4; ++ni)
      atomicAdd(&colsum[wn * 64 + ni * 16 + l15], csum[ni]);
    __syncthreads();
    if (t < 128) {
      const int col = col0 + t;
      const int c2 = col & 511;
      const int h = c2 >> 6, d = c2 & 63;
      const int bb = row0 >> 13;
      float* tgt = (col < 512) ? qsum : ksum;
      atomicAdd(&tgt[(bb * cH + h) * cD + d], colsum[t]);
    }
  }
}

// ---------------- K34: si, so; accumulate Sq, Sk (4 rows/wave/iter, float4) ----------------
__global__ __launch_bounds__(256) void k34_flow(const float* __restrict__ q,
      const float* __restrict__ k, const float* __restrict__ qsum,
      const float* __restrict__ ksum, float* __restrict__ si,
      float* __restrict__ Sq, float* __restrict__ Sk) {
  const int bh = blockIdx.x;
  const int n0 = blockIdx.y * 256;
  const int t = threadIdx.x;
  const int wave = t >> 6, lane = t & 63;
  const int g = lane >> 4, j = lane & 15;
  const float* qb = q + (size_t)bh * cN * cD;
  const float* kb = k + (size_t)bh * cN * cD;
  const float4 ks4 = *(const float4*)&ksum[bh * 64 + j * 4];
  const float4 qs4 = *(const float4*)&qsum[bh * 64 + j * 4];
  const float ksd[4] = {ks4.x + kEPS, ks4.y + kEPS, ks4.z + kEPS, ks4.w + kEPS};
  const float qsd[4] = {qs4.x + kEPS, qs4.y + kEPS, qs4.z + kEPS, qs4.w + kEPS};
  float aSq[4] = {}, aSk[4] = {};
  for (int i = 0; i < 16; ++i) {
    const int n = n0 + wave * 64 + i * 4 + g;
    const float4 q4 = *(const float4*)&qb[(size_t)n * cD + j * 4];
    const float4 k4 = *(const float4*)&kb[(size_t)n * cD + j * 4];
    const float qa[4] = {q4.x, q4.y, q4.z, q4.w};
    const float ka[4] = {k4.x, k4.y, k4.z, k4.w};
    float t1 = 0.f, t2 = 0.f;
    #pragma unroll
    for (int c = 0; c < 4; ++c) {
      t1 = fmaf(qa[c] + kEPS, ksd[c], t1);
      t2 = fmaf(ka[c] + kEPS, qsd[c], t2);
    }
    #pragma unroll
    for (int off = 1; off < 16; off <<= 1) {
      t1 += __shfl_xor(t1, off);
      t2 += __shfl_xor(t2, off);
    }
    const float si_n = 1.f / (t1 + kEPS);
    const float so_n = 1.f / (t2 + kEPS);
    if (j == 0) si[(size_t)bh * cN + n] = si_n;
    #pragma unroll
    for (int c = 0; c < 4; ++c) {
      aSq[c] = fmaf(qa[c], si_n, aSq[c]);
      aSk[c] = fmaf(ka[c], so_n, aSk[c]);
    }
  }
  #pragma unroll
  for (int c = 0; c < 4; ++c) {
    aSq[c] += __shfl_xor(aSq[c], 16); aSq[c] += __shfl_xor(aSq[c], 32);
    aSk[c] += __shfl_xor(aSk[c], 16); aSk[c] += __shfl_xor(aSk[c], 32);
  }
  __shared__ float sAq[4][64], sAk[4][64];
  if (g == 0) {
    #pragma unroll
    for (int c = 0; c < 4; ++c) { sAq[wave][j * 4 + c] = aSq[c]; sAk[wave][j * 4 + c] = aSk[c]; }
  }
  __syncthreads();
  if (t < 64) {
    atomicAdd(&Sq[bh * 64 + t], sAq[0][t] + sAq[1][t] + sAq[2][t] + sAq[3][t]);
    atomicAdd(&Sk[bh * 64 + t], sAk[0][t] + sAk[1][t] + sAk[2][t] + sAk[3][t]);
  }
}

// ---------------- K45: split-K kv partials (NO atomics), ev inline ----------------
// block (bh, y): kvpart[y][bh][64][64] = sum_{n in slice} k[n,:] (x) v[n,:]*ev[n]
__global__ __launch_bounds__(256) void k45_kv(const float* __restrict__ kk_,
      const float* __restrict__ vv, const float* __restrict__ Sq,
      float* __restrict__ kvpart, float* __restrict__ zpart) {
  const int bh = blockIdx.x;
  const int y = blockIdx.y;                       // KV_SPLIT slices
  constexpr int ROWS = cN / KV_SPLIT;             // 256
  const int n0 = y * ROWS;
  const int t = threadIdx.x;
  const int d = t & 63, eb = t >> 6;
  const int g = t >> 4, j = t & 15;               // 16 ev-groups of 16 lanes
  const int sr = t >> 4, sc = (t & 15) * 4;       // stage mapping
  const float* kb = kk_ + (size_t)bh * cN * cD;
  const float* vb = vv + (size_t)bh * cN * cD;
  const float4 sq4 = *(const float4*)&Sq[bh * 64 + j * 4];
  const float SqE[4] = {sq4.x + kEPS, sq4.y + kEPS, sq4.z + kEPS, sq4.w + kEPS};
  __shared__ float ks[32][64];
  __shared__ float vs[32][64];
  __shared__ float evs[32];
  __shared__ float zl[16];
  float acc[16] = {};
  float zacc = 0.f;
  // prefetch chunk 0 into registers (T14: issue early, write late)
  float4 pk0 = *(const float4*)&kb[(size_t)(n0 + sr) * cD + sc];
  float4 pk1 = *(const float4*)&kb[(size_t)(n0 + 16 + sr) * cD + sc];
  float4 pv0 = *(const float4*)&vb[(size_t)(n0 + sr) * cD + sc];
  float4 pv1 = *(const float4*)&vb[(size_t)(n0 + 16 + sr) * cD + sc];
  for (int c0 = 0; c0 < ROWS; c0 += 32) {
    __syncthreads();                               // prev FMA done
    *(float4*)&ks[sr][sc]      = pk0;
    *(float4*)&ks[sr + 16][sc] = pk1;
    *(float4*)&vs[sr][sc]      = pv0;
    *(float4*)&vs[sr + 16][sc] = pv1;
    __syncthreads();
    if (c0 + 32 < ROWS) {                          // issue next-chunk loads now
      pk0 = *(const float4*)&kb[(size_t)(n0 + c0 + 32 + sr) * cD + sc];
      pk1 = *(const float4*)&kb[(size_t)(n0 + c0 + 48 + sr) * cD + sc];
      pv0 = *(const float4*)&vb[(size_t)(n0 + c0 + 32 + sr) * cD + sc];
      pv1 = *(const float4*)&vb[(size_t)(n0 + c0 + 48 + sr) * cD + sc];
    }
    // ev for 32 rows: group g handles rows 2g, 2g+1
    #pragma unroll
    for (int rr = 0; rr < 2; ++rr) {
      const int r = g * 2 + rr;
      const float4 kk4 = *(const float4*)&ks[r][j * 4];
      float tt = 0.f;
      tt = fmaf(kk4.x + kEPS, SqE[0], tt);
      tt = fmaf(kk4.y + kEPS, SqE[1], tt);
      tt = fmaf(kk4.z + kEPS, SqE[2], tt);
      tt = fmaf(kk4.w + kEPS, SqE[3], tt);
      #pragma unroll
      for (int off = 1; off < 16; off <<= 1) tt += __shfl_xor(tt, off);
      if (j == 0) {
        const float cs = fminf(fmaxf(tt + kEPS, -1.f), 1.f);
        const float e = __expf(cs);
        evs[r] = e;
        zacc += e;
      }
    }
    __syncthreads();
    #pragma unroll
    for (int r = 0; r < 32; ++r) {
      const float kd = ks[r][d] * evs[r];
      #pragma unroll
      for (int j2 = 0; j2 < 16; ++j2)
        acc[j2] = fmaf(kd, vs[r][eb * 16 + j2], acc[j2]);
    }
  }
  if (j == 0) zl[g] = zacc;
  __syncthreads();
  if (t == 0) {
    float z = 0.f;
    #pragma unroll
    for (int i = 0; i < 16; ++i) z += zl[i];
    zpart[y * cBH + bh] = z;
  }
  float* kvb = kvpart + ((size_t)y * cBH + bh) * 4096 + d * 64 + eb * 16;
  #pragma unroll
  for (int j2 = 0; j2 < 16; ++j2) kvb[j2] = acc[j2];
}

// ---------------- K5R: fold split-K partials -> kvm, Zb (deterministic) ----------------
__global__ __launch_bounds__(256) void k5r_reduce(const float* __restrict__ kvpart,
      const float* __restrict__ zpart, float* __restrict__ kvm, float* __restrict__ Zb) {
  const int bh = blockIdx.x;
  const int t = threadIdx.x;
  for (int i = t; i < 4096; i += 256) {
    float s = 0.f;
    #pragma unroll
    for (int yy = 0; yy < KV_SPLIT; ++yy)
      s += kvpart[((size_t)yy * cBH + bh) * 4096 + i];
    kvm[(size_t)bh * 4096 + i] = s;
  }
  if (t == 0) {
    float z = 0.f;
    #pragma unroll
    for (int yy = 0; yy < KV_SPLIT; ++yy) z += zpart[yy * cBH + bh];
    Zb[bh] = z;
  }
}

// ---------------- K6b: xu = (q @ kv*(N/Z)) * si * sa -> split bf16 [M][512] ----------------
__global__ __launch_bounds__(256) void k6b_xu(const float* __restrict__ q,
      const float* __restrict__ kvmat, const float* __restrict__ si,
      const float* __restrict__ Sk, const float* __restrict__ Zb,
      ushort* __restrict__ xh, ushort* __restrict__ xl) {
  const int bh = blockIdx.x;
  const int b = bh >> 3, head = bh & 7;
  const int n0 = blockIdx.y * 64;
  const int lane = threadIdx.x & 63;
  const int wave = threadIdx.x >> 6;
  __shared__ float kvs[64][64];
  const float zs = (float)cN / Zb[bh];
  for (int i = threadIdx.x; i < 4096; i += 256)
    kvs[i >> 6][i & 63] = kvmat[(size_t)bh * 4096 + i] * zs;
  const float SkE = Sk[bh * 64 + lane] + kEPS;
  __syncthreads();
  const float* qb = q + (size_t)bh * cN * cD;
  for (int i = 0; i < 16; ++i) {
    const int n = n0 + wave * 16 + i;
    const float qd = qb[(size_t)n * cD + lane];
    float t2 = (qd + kEPS) * SkE;
    #pragma unroll
    for (int off = 1; off < 64; off <<= 1) t2 += __shfl_xor(t2, off);
    const float sa_n = 1.f / (1.f + __expf(-(t2 + kEPS)));
    float a0 = 0.f, a1 = 0.f, a2 = 0.f, a3 = 0.f;
    #pragma unroll
    for (int dd = 0; dd < 64; dd += 4) {
      a0 = fmaf(__shfl(qd, dd),     kvs[dd][lane],     a0);
      a1 = fmaf(__shfl(qd, dd + 1), kvs[dd + 1][lane], a1);
      a2 = fmaf(__shfl(qd, dd + 2), kvs[dd + 2][lane], a2);
      a3 = fmaf(__shfl(qd, dd + 3), kvs[dd + 3][lane], a3);
    }
    const float s = si[(size_t)bh * cN + n] * sa_n;
    const float val = ((a0 + a1) + (a2 + a3)) * s;
    ushort hbits, lbits;
    split2(val, hbits, lbits);
    const size_t m = (size_t)b * cN + n;
    xh[m * cC + head * 64 + lane] = hbits;
    xl[m * cC + head * 64 + lane] = lbits;
  }
}

extern "C" void kernel_launch(void* const* d_in, const int* in_sizes, int n_in,
                              void* d_out, int out_size, void* d_ws, size_t ws_size,
                              hipStream_t stream) {
  (void)in_sizes; (void)n_in; (void)out_size;
  const float* x     = (const float*)d_in[0];
  const float* Wqkv  = (const float*)d_in[1];
  const float* Wproj = (const float*)d_in[2];
  const float* bproj = (const float*)d_in[3];
  float* out = (float*)d_out;
  float* ws  = (float*)d_ws;

  const size_t SLAB = (size_t)cBH * cN * cD;       // 16,777,216 floats (64 MB)
  const size_t OFF_Q   = 0;
  const size_t OFF_K   = SLAB;
  const size_t OFF_V   = 2 * SLAB;                 // xu hi/lo alias v (dead after K45)
  const size_t OFF_ACC = 3 * SLAB;
  const size_t ACC_FLOATS = 2048 * 4 + 32 + (size_t)cBH * cD * cD;  // 139,296
  const size_t OFF_R   = OFF_ACC + ACC_FLOATS;     // time-shared region:
  // [wq hi+lo: 1.573M f32-equiv] -> [si: 0.262M] -> [wp hi+lo: 0.524M]
  const size_t R_FLOATS = (size_t)3 * cHD * cC;    // 1,572,864 floats (wq is largest)
  const size_t TOTAL   = OFF_R + R_FLOATS;         // 52.04M floats = 208.2 MB (proven fit)
  if (ws_size < TOTAL * sizeof(float)) return;

  float* q    = ws + OFF_Q;
  float* k    = ws + OFF_K;
  float* v    = ws + OFF_V;
  float* ksum = ws + OFF_ACC;
  float* qsum = ksum + 2048;
  float* Sk   = ksum + 4096;
  float* Sq   = ksum + 6144;
  float* Zb   = ksum + 8192;
  float* kvm  = ksum + 8224;

  // region R timeline: wq [split->gemm0] ; si [k34->k6b] ; wp [split->gemm1]
  ushort* wqh = (ushort*)(ws + OFF_R);
  ushort* wql = wqh + (size_t)3 * cHD * cC;
  float*  si  = ws + OFF_R;
  ushort* wph = (ushort*)(ws + OFF_R);
  ushort* wpl = wph + (size_t)cC * cHD;

  // xu bf16 hi/lo overlay the v slab (v dead after K45)
  ushort* xh = (ushort*)(ws + OFF_V);
  ushort* xl = xh + (size_t)cM * cHD;

  // k45 split-K partials live in d_out (only gemm1 writes d_out, at the end)
  float* kvpart = out;                                   // 32*32*4096 = 16 MB
  float* zpart  = out + (size_t)KV_SPLIT * cBH * 4096;   // 1024 floats

  hipMemsetAsync(ksum, 0, ACC_FLOATS * sizeof(float), stream);

  split_w<<<(3 * cHD * cC / 4 + 255) / 256, 256, 0, stream>>>(Wqkv, wqh, wql, 3 * cHD * cC / 4);
  gemm_mfma<0><<<dim3(cM / 128, (3 * cHD) / 128), 256, 0, stream>>>(
      x, nullptr, nullptr, wqh, wql, nullptr, q, k, v, qsum, ksum);
  k34_flow<<<dim3(cBH, cN / 256), 256, 0, stream>>>(q, k, qsum, ksum, si, Sq, Sk);
  k45_kv<<<dim3(cBH, KV_SPLIT), 256, 0, stream>>>(k, v, Sq, kvpart, zpart);
  k5r_reduce<<<cBH, 256, 0, stream>>>(kvpart, zpart, kvm, Zb);
  k6b_xu<<<dim3(cBH, cN / 64), 256, 0, stream>>>(q, kvm, si, Sk, Zb, xh, xl);
  split_w<<<(cC * cHD / 4 + 255) / 256, 256, 0, stream>>>(Wproj, wph, wpl, cC * cHD / 4);
  gemm_mfma<1><<<dim3(cM / 128, cHD / 128), 256, 0, stream>>>(
      nullptr, xh, xl, wph, wpl, bproj, out, nullptr, nullptr, nullptr, nullptr);
}